// Round 2
// baseline (444.434 us; speedup 1.0000x reference)
//
#include <hip/hip_runtime.h>

// SSIM, fused: reflect-pad(1) + five 3x3 box filters + elementwise formula.
// NCHW 32x3x384x640 fp32.
//
// v3: occupancy + vectorization together.
//  - v1 (98us): 24 VGPR, 8 waves/SIMD, but 6 scalar loads per output -> latency-bound.
//  - v2 (110us): float4 + 2-deep pipeline -> 116 VGPR -> 4 waves/SIMD, occupancy 20%.
//  - v3: VEC=2 (float2 loads), no manual double-buffer; rolling 3-row window of
//    5 horizontal sums x 2 cols = 30 state regs; total ~55 VGPR -> 8 waves/SIMD
//    (enforced via __launch_bounds__(256,8)). 4 waves/block, KROWS=12 ->
//    15360 waves = 60/CU of work over a 32/CU residency cap (~2 rounds).

constexpr int HH = 384;
constexpr int WW = 640;
constexpr int VEC = 2;              // columns per thread (float2)
constexpr int KROWS = 12;           // rows per thread; halo amortization 14/12
constexpr int WAVES = 4;            // waves per workgroup (stacked in y)
constexpr int BW = 64;              // threads per wave along w
constexpr float C1 = 0.01f * 0.01f;
constexpr float C2 = 0.03f * 0.03f;

typedef float f32x2 __attribute__((ext_vector_type(2)));

__global__ __launch_bounds__(BW * WAVES, 8) void ssim_kernel(
    const float* __restrict__ x,
    const float* __restrict__ y,
    float* __restrict__ out)
{
    const int tc = blockIdx.x * BW + threadIdx.x;   // 0..319, exact fit
    const int c0 = tc * VEC;                        // 0..638
    const int h0 = (blockIdx.y * WAVES + threadIdx.y) * KROWS;
    const size_t pbase = (size_t)blockIdx.z * (size_t)(HH * WW);
    const float* __restrict__ xp = x + pbase;
    const float* __restrict__ yp = y + pbase;
    float* __restrict__ op = out + pbase;

    // reflect (jnp 'reflect': edge NOT repeated): -1 -> 1, W -> W-2
    const int wl = (c0 == 0) ? 1 : (c0 - 1);
    const int wr = (c0 + VEC >= WW) ? (WW - 2) : (c0 + VEC);

    // rolling 3-row window of horizontal 3-tap sums, 2 columns each
    float hx[3][2], hy[3][2], hxx[3][2], hyy[3][2], hxy[3][2];

#define ROW(R, J) do {                                                   \
        int rr = (R);                                                    \
        rr = (rr < 0) ? 1 : ((rr >= HH) ? (HH - 2) : rr);                \
        const float* __restrict__ xr = xp + (size_t)rr * WW;             \
        const float* __restrict__ yr = yp + (size_t)rr * WW;             \
        const f32x2 vx = *reinterpret_cast<const f32x2*>(xr + c0);       \
        const f32x2 vy = *reinterpret_cast<const f32x2*>(yr + c0);       \
        const float xl = xr[wl], xh = xr[wr];                            \
        const float yl = yr[wl], yh = yr[wr];                            \
        const float xm = vx.x + vx.y;                                    \
        const float ym = vy.x + vy.y;                                    \
        const float xxm = vx.x * vx.x + vx.y * vx.y;                     \
        const float yym = vy.x * vy.x + vy.y * vy.y;                     \
        const float xym = vx.x * vy.x + vx.y * vy.y;                     \
        hx[J][0]  = xl + xm;          hx[J][1]  = xm + xh;               \
        hy[J][0]  = yl + ym;          hy[J][1]  = ym + yh;               \
        hxx[J][0] = xl * xl + xxm;    hxx[J][1] = xxm + xh * xh;         \
        hyy[J][0] = yl * yl + yym;    hyy[J][1] = yym + yh * yh;         \
        hxy[J][0] = xl * yl + xym;    hxy[J][1] = xym + xh * yh;         \
    } while (0)

    ROW(h0 - 1, 0);
    ROW(h0,     1);

    const float inv9 = 1.0f / 9.0f;

#pragma unroll
    for (int i = 0; i < KROWS; ++i) {
        ROW(h0 + i + 1, (i + 2) % 3);

        float o[VEC];
#pragma unroll
        for (int c = 0; c < VEC; ++c) {
            const float sx  = hx[0][c]  + hx[1][c]  + hx[2][c];
            const float sy  = hy[0][c]  + hy[1][c]  + hy[2][c];
            const float sxx = hxx[0][c] + hxx[1][c] + hxx[2][c];
            const float syy = hyy[0][c] + hyy[1][c] + hyy[2][c];
            const float sxy = hxy[0][c] + hxy[1][c] + hxy[2][c];

            const float mux = sx * inv9;
            const float muy = sy * inv9;
            const float varx = sxx * inv9 - mux * mux;
            const float vary = syy * inv9 - muy * muy;
            const float cov  = sxy * inv9 - mux * muy;

            const float num = (2.0f * mux * muy + C1) * (2.0f * cov + C2);
            const float den = (mux * mux + muy * muy + C1) * (varx + vary + C2);
            float s = num / den;
            o[c] = fminf(fmaxf(s, 0.0f), 1.0f);
        }

        f32x2 ov;
        ov.x = o[0]; ov.y = o[1];
        __builtin_nontemporal_store(
            ov, reinterpret_cast<f32x2*>(op + (size_t)(h0 + i) * WW + c0));
    }
#undef ROW
}

extern "C" void kernel_launch(void* const* d_in, const int* in_sizes, int n_in,
                              void* d_out, int out_size, void* d_ws, size_t ws_size,
                              hipStream_t stream) {
    const float* x = (const float*)d_in[0];
    const float* y = (const float*)d_in[1];
    float* out = (float*)d_out;

    const int planes = in_sizes[0] / (HH * WW);            // 32*3 = 96
    dim3 grid(WW / (VEC * BW), HH / (KROWS * WAVES), planes);  // (5, 8, 96)
    dim3 block(BW, WAVES);
    ssim_kernel<<<grid, block, 0, stream>>>(x, y, out);
}

// Round 3
// 249.180 us; speedup vs baseline: 1.7836x; 1.7836x over previous
//
#include <hip/hip_runtime.h>

// SSIM, fused: reflect-pad(1) + five 3x3 box filters + elementwise formula.
// NCHW 32x3x384x640 fp32.
//
// v4: fix v3's scratch-spill catastrophe.
//  - v3 (301us): __launch_bounds__(256,8) cap -> compiler declined the 12x unroll
//    -> (i+2)%3 became runtime index -> rolling arrays demoted to scratch
//    (VGPR=32, WRITE_SIZE 5.6x, FETCH 3x = spill round-trips).
//  - v4: group-of-3 row rotation with LITERAL array indices (scratch-proof even
//    if the group loop is not unrolled), and no min-waves cap (natural VGPR).
//  - Keeps v3's good parts: float2 loads (1/3 the load instrs of v1/output),
//    4 waves/block, nontemporal stores.

constexpr int HH = 384;
constexpr int WW = 640;
constexpr int VEC = 2;              // columns per thread (float2)
constexpr int KROWS = 12;           // rows per thread (multiple of 3); halo 14/12
constexpr int WAVES = 4;            // waves per workgroup (stacked in y)
constexpr int BW = 64;              // threads per wave along w
constexpr float C1 = 0.01f * 0.01f;
constexpr float C2 = 0.03f * 0.03f;

typedef float f32x2 __attribute__((ext_vector_type(2)));

__global__ __launch_bounds__(BW * WAVES) void ssim_kernel(
    const float* __restrict__ x,
    const float* __restrict__ y,
    float* __restrict__ out)
{
    const int tc = blockIdx.x * BW + threadIdx.x;   // 0..319, exact fit
    const int c0 = tc * VEC;                        // 0..638
    const int h0 = (blockIdx.y * WAVES + threadIdx.y) * KROWS;
    const size_t pbase = (size_t)blockIdx.z * (size_t)(HH * WW);
    const float* __restrict__ xp = x + pbase;
    const float* __restrict__ yp = y + pbase;
    float* __restrict__ op = out + pbase;

    // reflect (jnp 'reflect': edge NOT repeated): -1 -> 1, W -> W-2
    const int wl = (c0 == 0) ? 1 : (c0 - 1);
    const int wr = (c0 + VEC >= WW) ? (WW - 2) : (c0 + VEC);

    // rolling 3-row window of horizontal 3-tap sums, 2 columns each.
    // ALL indices below are literal constants -> guaranteed register allocation.
    float hx[3][2], hy[3][2], hxx[3][2], hyy[3][2], hxy[3][2];

#define ROW(R, J) do {                                                   \
        int rr = (R);                                                    \
        rr = (rr < 0) ? 1 : ((rr >= HH) ? (HH - 2) : rr);                \
        const float* __restrict__ xr = xp + (size_t)rr * WW;             \
        const float* __restrict__ yr = yp + (size_t)rr * WW;             \
        const f32x2 vx = *reinterpret_cast<const f32x2*>(xr + c0);       \
        const f32x2 vy = *reinterpret_cast<const f32x2*>(yr + c0);       \
        const float xl = xr[wl], xh = xr[wr];                            \
        const float yl = yr[wl], yh = yr[wr];                            \
        const float xm = vx.x + vx.y;                                    \
        const float ym = vy.x + vy.y;                                    \
        const float xxm = vx.x * vx.x + vx.y * vx.y;                     \
        const float yym = vy.x * vy.x + vy.y * vy.y;                     \
        const float xym = vx.x * vy.x + vx.y * vy.y;                     \
        hx[J][0]  = xl + xm;          hx[J][1]  = xm + xh;               \
        hy[J][0]  = yl + ym;          hy[J][1]  = ym + yh;               \
        hxx[J][0] = xl * xl + xxm;    hxx[J][1] = xxm + xh * xh;         \
        hyy[J][0] = yl * yl + yym;    hyy[J][1] = yym + yh * yh;         \
        hxy[J][0] = xl * yl + xym;    hxy[J][1] = xym + xh * yh;         \
    } while (0)

#define EMIT(HR) do {                                                    \
        float o[VEC];                                                    \
        _Pragma("unroll")                                                \
        for (int c = 0; c < VEC; ++c) {                                  \
            const float sx  = hx[0][c]  + hx[1][c]  + hx[2][c];          \
            const float sy  = hy[0][c]  + hy[1][c]  + hy[2][c];          \
            const float sxx = hxx[0][c] + hxx[1][c] + hxx[2][c];         \
            const float syy = hyy[0][c] + hyy[1][c] + hyy[2][c];         \
            const float sxy = hxy[0][c] + hxy[1][c] + hxy[2][c];         \
            const float mux = sx * inv9;                                 \
            const float muy = sy * inv9;                                 \
            const float varx = sxx * inv9 - mux * mux;                   \
            const float vary = syy * inv9 - muy * muy;                   \
            const float cov  = sxy * inv9 - mux * muy;                   \
            const float num = (2.0f * mux * muy + C1) * (2.0f * cov + C2); \
            const float den = (mux * mux + muy * muy + C1)               \
                              * (varx + vary + C2);                      \
            float s = num / den;                                         \
            o[c] = fminf(fmaxf(s, 0.0f), 1.0f);                          \
        }                                                                \
        f32x2 ov; ov.x = o[0]; ov.y = o[1];                              \
        __builtin_nontemporal_store(                                     \
            ov, reinterpret_cast<f32x2*>(op + (size_t)(HR) * WW + c0));  \
    } while (0)

    const float inv9 = 1.0f / 9.0f;

    ROW(h0 - 1, 0);
    ROW(h0,     1);

#pragma unroll
    for (int g = 0; g < KROWS / 3; ++g) {
        const int hb = h0 + 3 * g;
        // 3-step rotation with literal window indices:
        ROW(hb + 1, 2); EMIT(hb + 0);
        ROW(hb + 2, 0); EMIT(hb + 1);
        ROW(hb + 3, 1); EMIT(hb + 2);
    }
#undef ROW
#undef EMIT
}

extern "C" void kernel_launch(void* const* d_in, const int* in_sizes, int n_in,
                              void* d_out, int out_size, void* d_ws, size_t ws_size,
                              hipStream_t stream) {
    const float* x = (const float*)d_in[0];
    const float* y = (const float*)d_in[1];
    float* out = (float*)d_out;

    const int planes = in_sizes[0] / (HH * WW);            // 32*3 = 96
    dim3 grid(WW / (VEC * BW), HH / (KROWS * WAVES), planes);  // (5, 8, 96)
    dim3 block(BW, WAVES);
    ssim_kernel<<<grid, block, 0, stream>>>(x, y, out);
}

// Round 5
// 241.729 us; speedup vs baseline: 1.8386x; 1.0308x over previous
//
#include <hip/hip_runtime.h>

// SSIM, fused: reflect-pad(1) + five 3x3 box filters + elementwise formula.
// NCHW 32x3x384x640 fp32.
//
// v6 = v5 with the TCOLS compile error fixed (launch config only).
//  - v4 (103us/dispatch): 6 VMEM per row, full-precision div, 2.4 TB/s plateau.
//  - v5/v6: the 4 taps for 2 output cols are contiguous [c0-1 .. c0+2] -> ONE
//    dword-aligned dwordx4 per array per row. 6 VMEM -> 2 VMEM.
//    Image-edge lanes only exist in blockIdx.x 0 and last -> template<EDGE>
//    clone selected by a wave-uniform scalar branch; interior blocks pay zero.
//  - 1-row software pipeline via two named f32x4 buffers (all literal indices,
//    scratch-proof; +8 VGPR only).
//  - SSIM ratio multiplied through by 81^2: works on raw window sums, no
//    mu/var/cov materialization; fast v_rcp_f32 instead of IEEE div sequence
//    (rel err ~1e-5 << 0.0039 tolerance).

constexpr int HH = 384;
constexpr int WW = 640;
constexpr int VEC = 2;              // output columns per thread
constexpr int TCOLS = WW / VEC;     // 320 thread-columns per image row
constexpr int KROWS = 12;           // rows per thread (multiple of 6)
constexpr int WAVES = 2;            // waves per workgroup
constexpr int BW = 64;              // threads per wave
constexpr float C1 = 0.01f * 0.01f;
constexpr float C2 = 0.03f * 0.03f;
constexpr float K1 = 81.0f * C1;    // 0.0081f
constexpr float K2 = 81.0f * C2;    // 0.0729f

typedef float f32x4 __attribute__((ext_vector_type(4)));
typedef float f32x2 __attribute__((ext_vector_type(2)));

template<bool EDGE>
__device__ __forceinline__ void ssim_body(
    const float* __restrict__ xp, const float* __restrict__ yp,
    float* __restrict__ op, int c0, int h0, bool ledge, bool redge)
{
    // one dwordx4 covers taps [c0-1 .. c0+2]; edge lanes re-wire elements
    const int lbase = ledge ? 0 : (redge ? (WW - 4) : (c0 - 1));

    // rolling 3-row window of horizontal 3-tap sums, 2 cols. Literal indices only.
    float hx[3][2], hy[3][2], hxx[3][2], hyy[3][2], hxy[3][2];
    f32x4 ax, ay, bx, by;           // double-buffered raw rows (pipeline depth 1)

#define LOADR(R, VX, VY) do {                                            \
        int rr = (R);                                                    \
        rr = (rr < 0) ? 1 : ((rr >= HH) ? (HH - 2) : rr);                \
        const float* __restrict__ xr = xp + (size_t)rr * WW;             \
        const float* __restrict__ yr = yp + (size_t)rr * WW;             \
        VX = *reinterpret_cast<const f32x4*>(xr + lbase);                \
        VY = *reinterpret_cast<const f32x4*>(yr + lbase);                \
    } while (0)

#define HSUMT(J, VX, VY) do {                                            \
        float a0, a1, a2, a3, b0, b1, b2, b3;                            \
        if constexpr (EDGE) {                                            \
            const bool e = ledge || redge;                               \
            a0 = e ? VX.y : VX.x;                                        \
            a1 = ledge ? VX.x : (redge ? VX.z : VX.y);                   \
            a2 = ledge ? VX.y : (redge ? VX.w : VX.z);                   \
            a3 = e ? VX.z : VX.w;                                        \
            b0 = e ? VY.y : VY.x;                                        \
            b1 = ledge ? VY.x : (redge ? VY.z : VY.y);                   \
            b2 = ledge ? VY.y : (redge ? VY.w : VY.z);                   \
            b3 = e ? VY.z : VY.w;                                        \
        } else {                                                         \
            a0 = VX.x; a1 = VX.y; a2 = VX.z; a3 = VX.w;                  \
            b0 = VY.x; b1 = VY.y; b2 = VY.z; b3 = VY.w;                  \
        }                                                                \
        const float mx  = a1 + a2;                                       \
        const float my  = b1 + b2;                                       \
        const float mxx = __builtin_fmaf(a1, a1, a2 * a2);               \
        const float myy = __builtin_fmaf(b1, b1, b2 * b2);               \
        const float mxy = __builtin_fmaf(a1, b1, a2 * b2);               \
        hx[J][0]  = mx + a0;                     hx[J][1]  = mx + a3;    \
        hy[J][0]  = my + b0;                     hy[J][1]  = my + b3;    \
        hxx[J][0] = __builtin_fmaf(a0, a0, mxx); hxx[J][1] = __builtin_fmaf(a3, a3, mxx); \
        hyy[J][0] = __builtin_fmaf(b0, b0, myy); hyy[J][1] = __builtin_fmaf(b3, b3, myy); \
        hxy[J][0] = __builtin_fmaf(a0, b0, mxy); hxy[J][1] = __builtin_fmaf(a3, b3, mxy); \
    } while (0)

    // SSIM on raw sums: ratio multiplied through by 81^2.
    //   num = (2*Sx*Sy + 81C1) * (18*Sxy - 2*Sx*Sy + 81C2)
    //   den = (Sx^2+Sy^2 + 81C1) * (9*(Sxx+Syy) - Sx^2 - Sy^2 + 81C2)
#define EMIT(HR) do {                                                    \
        float o[2];                                                      \
        _Pragma("unroll")                                                \
        for (int c = 0; c < 2; ++c) {                                    \
            const float Sx  = hx[0][c]  + hx[1][c]  + hx[2][c];          \
            const float Sy  = hy[0][c]  + hy[1][c]  + hy[2][c];          \
            const float Sxx = hxx[0][c] + hxx[1][c] + hxx[2][c];         \
            const float Syy = hyy[0][c] + hyy[1][c] + hyy[2][c];         \
            const float Sxy = hxy[0][c] + hxy[1][c] + hxy[2][c];         \
            const float t    = Sx * Sy;                                  \
            const float p    = __builtin_fmaf(Sx, Sx, Sy * Sy);          \
            const float q    = Sxx + Syy;                                \
            const float numA = __builtin_fmaf(2.0f, t, K1);              \
            const float numB = __builtin_fmaf(-2.0f, t,                  \
                                   __builtin_fmaf(18.0f, Sxy, K2));      \
            const float denA = p + K1;                                   \
            const float denB = __builtin_fmaf(9.0f, q, K2) - p;          \
            const float s = (numA * numB)                                \
                            * __builtin_amdgcn_rcpf(denA * denB);        \
            o[c] = fminf(fmaxf(s, 0.0f), 1.0f);                          \
        }                                                                \
        f32x2 ov; ov.x = o[0]; ov.y = o[1];                              \
        __builtin_nontemporal_store(                                     \
            ov, reinterpret_cast<f32x2*>(op + (size_t)(HR) * WW + c0));  \
    } while (0)

    LOADR(h0 - 1, ax, ay);
    LOADR(h0,     bx, by);
    HSUMT(0, ax, ay);
    HSUMT(1, bx, by);
    LOADR(h0 + 1, ax, ay);

    // 6-row groups: 3-slot rotation x A/B buffer parity, all indices literal.
#pragma unroll
    for (int g = 0; g < KROWS / 6; ++g) {
        const int hb = h0 + 6 * g;
        const bool last = (g == KROWS / 6 - 1);   // const-folded under unroll
        LOADR(hb + 2, bx, by); HSUMT(2, ax, ay); EMIT(hb + 0);
        LOADR(hb + 3, ax, ay); HSUMT(0, bx, by); EMIT(hb + 1);
        LOADR(hb + 4, bx, by); HSUMT(1, ax, ay); EMIT(hb + 2);
        LOADR(hb + 5, ax, ay); HSUMT(2, bx, by); EMIT(hb + 3);
        LOADR(hb + 6, bx, by); HSUMT(0, ax, ay); EMIT(hb + 4);
        if (!last) LOADR(hb + 7, ax, ay);         // skip the one-past load at end
        HSUMT(1, bx, by); EMIT(hb + 5);
    }
#undef LOADR
#undef HSUMT
#undef EMIT
}

__global__ __launch_bounds__(BW * WAVES) void ssim_kernel(
    const float* __restrict__ x, const float* __restrict__ y,
    float* __restrict__ out)
{
    const int tc = blockIdx.x * BW + threadIdx.x;   // 0..319
    const int c0 = tc * VEC;                        // 0..638
    const int h0 = (blockIdx.y * WAVES + threadIdx.y) * KROWS;
    const size_t pbase = (size_t)blockIdx.z * (size_t)(HH * WW);

    const bool ledge = (c0 == 0);
    const bool redge = (c0 == WW - VEC);

    // image-edge lanes exist only in the first and last x-blocks;
    // wave-uniform scalar branch -> interior blocks run the select-free clone
    if (blockIdx.x == 0 || blockIdx.x == gridDim.x - 1)
        ssim_body<true >(x + pbase, y + pbase, out + pbase, c0, h0, ledge, redge);
    else
        ssim_body<false>(x + pbase, y + pbase, out + pbase, c0, h0, ledge, redge);
}

extern "C" void kernel_launch(void* const* d_in, const int* in_sizes, int n_in,
                              void* d_out, int out_size, void* d_ws, size_t ws_size,
                              hipStream_t stream) {
    const float* x = (const float*)d_in[0];
    const float* y = (const float*)d_in[1];
    float* out = (float*)d_out;

    const int planes = in_sizes[0] / (HH * WW);                // 32*3 = 96
    dim3 grid(TCOLS / BW, HH / (KROWS * WAVES), planes);       // (5, 16, 96)
    dim3 block(BW, WAVES);
    ssim_kernel<<<grid, block, 0, stream>>>(x, y, out);
}

// Round 6
// 233.641 us; speedup vs baseline: 1.9022x; 1.0346x over previous
//
#include <hip/hip_runtime.h>

// SSIM, fused: reflect-pad(1) + five 3x3 box filters + elementwise formula.
// NCHW 32x3x384x640 fp32.
//
// v7: concurrency push. Evidence: v1/v4/v6 all pin at ~99us / 2.5 TB/s despite
// 6x different VMEM mix and 1.6x different VALU -> not issue-limited. v3 (the
// spill kernel) sustained 3.24 TB/s at 84% occupancy / 120 waves-of-work per CU
// -> the memory system goes faster when more waves are resident. BW tracks
// occupancy tracks total waves/CU across all five runs.
//  - KROWS=6: 64 y-strips -> 30720 waves = 120/CU (2x v6).
//  - Pipeline depth 2: three buffer pairs, loads issued 2 rows ahead ->
//    4 KB/wave in flight at every consume point (v6: 2 KB).
//  - Flat schedule (no inner loop), every array index literal: scratch-proof.
//  - Keeps v6's lean body: one dwordx4 per array per row covering taps
//    [c0-1..c0+2], template<EDGE> clones, 81^2-scaled SSIM on raw sums,
//    v_rcp_f32, nontemporal f32x2 stores (keep inputs L3-resident).

constexpr int HH = 384;
constexpr int WW = 640;
constexpr int VEC = 2;              // output columns per thread
constexpr int TCOLS = WW / VEC;     // 320 thread-columns per image row
constexpr int KROWS = 6;            // rows per thread; halo 8/6
constexpr int WAVES = 2;            // waves per workgroup
constexpr int BW = 64;              // threads per wave
constexpr float C1 = 0.01f * 0.01f;
constexpr float C2 = 0.03f * 0.03f;
constexpr float K1 = 81.0f * C1;    // 0.0081f
constexpr float K2 = 81.0f * C2;    // 0.0729f

typedef float f32x4 __attribute__((ext_vector_type(4)));
typedef float f32x2 __attribute__((ext_vector_type(2)));

template<bool EDGE>
__device__ __forceinline__ void ssim_body(
    const float* __restrict__ xp, const float* __restrict__ yp,
    float* __restrict__ op, int c0, int h0, bool ledge, bool redge)
{
    // one dwordx4 covers taps [c0-1 .. c0+2]; edge lanes re-wire elements
    const int lbase = ledge ? 0 : (redge ? (WW - 4) : (c0 - 1));

    // rolling 3-row window of horizontal 3-tap sums, 2 cols. Literal indices only.
    float hx[3][2], hy[3][2], hxx[3][2], hyy[3][2], hxy[3][2];
    // three raw-row buffer pairs: pipeline depth 2 (row r lives in buffer r%3)
    f32x4 b0x, b0y, b1x, b1y, b2x, b2y;

#define LOADR(R, VX, VY) do {                                            \
        int rr = (R);                                                    \
        rr = (rr < 0) ? 1 : ((rr >= HH) ? (HH - 2) : rr);                \
        const float* __restrict__ xr = xp + (size_t)rr * WW;             \
        const float* __restrict__ yr = yp + (size_t)rr * WW;             \
        VX = *reinterpret_cast<const f32x4*>(xr + lbase);                \
        VY = *reinterpret_cast<const f32x4*>(yr + lbase);                \
    } while (0)

#define HSUMT(J, VX, VY) do {                                            \
        float a0, a1, a2, a3, b0, b1, b2, b3;                            \
        if constexpr (EDGE) {                                            \
            const bool e = ledge || redge;                               \
            a0 = e ? VX.y : VX.x;                                        \
            a1 = ledge ? VX.x : (redge ? VX.z : VX.y);                   \
            a2 = ledge ? VX.y : (redge ? VX.w : VX.z);                   \
            a3 = e ? VX.z : VX.w;                                        \
            b0 = e ? VY.y : VY.x;                                        \
            b1 = ledge ? VY.x : (redge ? VY.z : VY.y);                   \
            b2 = ledge ? VY.y : (redge ? VY.w : VY.z);                   \
            b3 = e ? VY.z : VY.w;                                        \
        } else {                                                         \
            a0 = VX.x; a1 = VX.y; a2 = VX.z; a3 = VX.w;                  \
            b0 = VY.x; b1 = VY.y; b2 = VY.z; b3 = VY.w;                  \
        }                                                                \
        const float mx  = a1 + a2;                                       \
        const float my  = b1 + b2;                                       \
        const float mxx = __builtin_fmaf(a1, a1, a2 * a2);               \
        const float myy = __builtin_fmaf(b1, b1, b2 * b2);               \
        const float mxy = __builtin_fmaf(a1, b1, a2 * b2);               \
        hx[J][0]  = mx + a0;                     hx[J][1]  = mx + a3;    \
        hy[J][0]  = my + b0;                     hy[J][1]  = my + b3;    \
        hxx[J][0] = __builtin_fmaf(a0, a0, mxx); hxx[J][1] = __builtin_fmaf(a3, a3, mxx); \
        hyy[J][0] = __builtin_fmaf(b0, b0, myy); hyy[J][1] = __builtin_fmaf(b3, b3, myy); \
        hxy[J][0] = __builtin_fmaf(a0, b0, mxy); hxy[J][1] = __builtin_fmaf(a3, b3, mxy); \
    } while (0)

    // SSIM on raw sums: ratio multiplied through by 81^2.
    //   num = (2*Sx*Sy + 81C1) * (18*Sxy - 2*Sx*Sy + 81C2)
    //   den = (Sx^2+Sy^2 + 81C1) * (9*(Sxx+Syy) - Sx^2 - Sy^2 + 81C2)
#define EMIT(HR) do {                                                    \
        float o[2];                                                      \
        _Pragma("unroll")                                                \
        for (int c = 0; c < 2; ++c) {                                    \
            const float Sx  = hx[0][c]  + hx[1][c]  + hx[2][c];          \
            const float Sy  = hy[0][c]  + hy[1][c]  + hy[2][c];          \
            const float Sxx = hxx[0][c] + hxx[1][c] + hxx[2][c];         \
            const float Syy = hyy[0][c] + hyy[1][c] + hyy[2][c];         \
            const float Sxy = hxy[0][c] + hxy[1][c] + hxy[2][c];         \
            const float t    = Sx * Sy;                                  \
            const float p    = __builtin_fmaf(Sx, Sx, Sy * Sy);          \
            const float q    = Sxx + Syy;                                \
            const float numA = __builtin_fmaf(2.0f, t, K1);              \
            const float numB = __builtin_fmaf(-2.0f, t,                  \
                                   __builtin_fmaf(18.0f, Sxy, K2));      \
            const float denA = p + K1;                                   \
            const float denB = __builtin_fmaf(9.0f, q, K2) - p;          \
            const float s = (numA * numB)                                \
                            * __builtin_amdgcn_rcpf(denA * denB);        \
            o[c] = fminf(fmaxf(s, 0.0f), 1.0f);                          \
        }                                                                \
        f32x2 ov; ov.x = o[0]; ov.y = o[1];                              \
        __builtin_nontemporal_store(                                     \
            ov, reinterpret_cast<f32x2*>(op + (size_t)(HR) * WW + c0));  \
    } while (0)

    // Flat depth-2 schedule; row r -> buffer/slot r%3 (h0 % 3 == 0).
    // At every HSUMT, the next two rows' loads are in flight (4 VMEM).
    LOADR(h0 - 1, b2x, b2y);
    LOADR(h0,     b0x, b0y);
    LOADR(h0 + 1, b1x, b1y);  HSUMT(2, b2x, b2y);
    LOADR(h0 + 2, b2x, b2y);  HSUMT(0, b0x, b0y);
    LOADR(h0 + 3, b0x, b0y);  HSUMT(1, b1x, b1y);  EMIT(h0 + 0);
    LOADR(h0 + 4, b1x, b1y);  HSUMT(2, b2x, b2y);  EMIT(h0 + 1);
    LOADR(h0 + 5, b2x, b2y);  HSUMT(0, b0x, b0y);  EMIT(h0 + 2);
    LOADR(h0 + 6, b0x, b0y);  HSUMT(1, b1x, b1y);  EMIT(h0 + 3);
                              HSUMT(2, b2x, b2y);  EMIT(h0 + 4);
                              HSUMT(0, b0x, b0y);  EMIT(h0 + 5);
#undef LOADR
#undef HSUMT
#undef EMIT
}

__global__ __launch_bounds__(BW * WAVES) void ssim_kernel(
    const float* __restrict__ x, const float* __restrict__ y,
    float* __restrict__ out)
{
    const int tc = blockIdx.x * BW + threadIdx.x;   // 0..319
    const int c0 = tc * VEC;                        // 0..638
    const int h0 = (blockIdx.y * WAVES + threadIdx.y) * KROWS;
    const size_t pbase = (size_t)blockIdx.z * (size_t)(HH * WW);

    const bool ledge = (c0 == 0);
    const bool redge = (c0 == WW - VEC);

    // image-edge lanes exist only in the first and last x-blocks;
    // wave-uniform scalar branch -> interior blocks run the select-free clone
    if (blockIdx.x == 0 || blockIdx.x == gridDim.x - 1)
        ssim_body<true >(x + pbase, y + pbase, out + pbase, c0, h0, ledge, redge);
    else
        ssim_body<false>(x + pbase, y + pbase, out + pbase, c0, h0, ledge, redge);
}

extern "C" void kernel_launch(void* const* d_in, const int* in_sizes, int n_in,
                              void* d_out, int out_size, void* d_ws, size_t ws_size,
                              hipStream_t stream) {
    const float* x = (const float*)d_in[0];
    const float* y = (const float*)d_in[1];
    float* out = (float*)d_out;

    const int planes = in_sizes[0] / (HH * WW);                // 32*3 = 96
    dim3 grid(TCOLS / BW, HH / (KROWS * WAVES), planes);       // (5, 32, 96)
    dim3 block(BW, WAVES);
    ssim_kernel<<<grid, block, 0, stream>>>(x, y, out);
}